// Round 1
// baseline (11113.329 us; speedup 1.0000x reference)
//
#include <hip/hip_runtime.h>
#include <math.h>

#define WSZ 7
#define SHIFT 3
#define NH 6
#define NN 49            // WSZ*WSZ
#define CCH 192
#define DD 32            // CCH/NH
#define IMG 224
#define NWIN 8192        // 8 * 32 * 32
#define BLOCK 768        // 12 waves
#define CP 196           // padded LDS row (floats), 16B-aligned rows, conflict-free
#define ATTP 52

#define OUT_ELEMS 77070336   // 8*224*224*192

struct __align__(16) SMem {
  float q[NN][CP];     // later aliased as attention-output accumulator
  float k[NN][CP];
  float v[NN][CP];
  float att[NN][ATTP];
  float mw[NN];
  float logmw[NN];
};

__device__ __forceinline__ float wave_reduce_max(float v) {
#pragma unroll
  for (int off = 32; off >= 1; off >>= 1)
    v = fmaxf(v, __shfl_xor(v, off, 64));
  return v;
}
__device__ __forceinline__ float wave_reduce_sum(float v) {
#pragma unroll
  for (int off = 32; off >= 1; off >>= 1)
    v += __shfl_xor(v, off, 64);
  return v;
}

__launch_bounds__(BLOCK, 1)
__global__ void swin_cross_attn_kernel(
    const float* __restrict__ x, const float* __restrict__ y,
    const float* __restrict__ Wq, const float* __restrict__ Wk,
    const float* __restrict__ Wv, const float* __restrict__ Wo,
    float* __restrict__ out, float* __restrict__ att_out)
{
  extern __shared__ char smem_raw[];
  SMem& sm = *reinterpret_cast<SMem*>(smem_raw);

  const int w   = blockIdx.x;
  const int b   = w >> 10;        // / (32*32)
  const int wi  = (w >> 5) & 31;
  const int wj  = w & 31;
  const int tid = threadIdx.x;
  const int lane = tid & 63;
  const int wave = tid >> 6;

  // ---------- Phase 0: overexposure mask per window pixel ----------
  // mask[n] = mean_c( x > 0.95 ? 0 : 1 ), computed from RAW x at gather coords.
  for (int n = wave; n < NN; n += 12) {
    const int grow = (wi * WSZ + n / WSZ + SHIFT) % IMG;   // roll(-SHIFT) gather
    const int gcol = (wj * WSZ + n % WSZ + SHIFT) % IMG;
    const int gb = ((b * IMG + grow) * IMG + gcol) * CCH;
    float cnt = 0.f;
    if (lane < 48) {
      const float4 xv = *reinterpret_cast<const float4*>(x + gb + lane * 4);
      cnt = (xv.x > 0.95f ? 0.f : 1.f) + (xv.y > 0.95f ? 0.f : 1.f)
          + (xv.z > 0.95f ? 0.f : 1.f) + (xv.w > 0.95f ? 0.f : 1.f);
    }
    cnt = wave_reduce_sum(cnt);
    if (lane == 0) {
      const float m = cnt * (1.0f / 192.0f);
      sm.mw[n] = m;
      sm.logmw[n] = logf(m + 1e-6f);
    }
  }
  __syncthreads();

  // ---------- Projections: column-owned, rows register-blocked ----------
  // thread -> (nt = row-quarter, co = output column); every wave is nt-uniform
  // so the x/y loads below are wave-uniform broadcasts (single L1/L2 fetch).
  const int co = tid % CCH;
  const int nt = tid / CCH;              // 0..3
  const int n0 = (nt * NN) >> 2;         // 0,12,24,36
  const int n1 = ((nt + 1) * NN) >> 2;   // 12,24,36,49
  const int nrows = n1 - n0;             // 12 or 13

  int gbase[13];
  for (int i = 0; i < nrows; ++i) {
    const int n = n0 + i;
    const int grow = (wi * WSZ + n / WSZ + SHIFT) % IMG;
    const int gcol = (wj * WSZ + n % WSZ + SHIFT) % IMG;
    gbase[i] = ((b * IMG + grow) * IMG + gcol) * CCH;
  }

  // q = (x @ Wq) * mw[n]   (mask factored out of the matmul)
  {
    float acc[13];
#pragma unroll
    for (int i = 0; i < 13; ++i) acc[i] = 0.f;
#pragma unroll 2
    for (int c4 = 0; c4 < 48; ++c4) {
      const float w0 = Wq[(c4 * 4 + 0) * CCH + co];
      const float w1 = Wq[(c4 * 4 + 1) * CCH + co];
      const float w2 = Wq[(c4 * 4 + 2) * CCH + co];
      const float w3 = Wq[(c4 * 4 + 3) * CCH + co];
#pragma unroll
      for (int i = 0; i < 13; ++i) {
        if (i < nrows) {
          const float4 xv = *reinterpret_cast<const float4*>(x + gbase[i] + c4 * 4);
          float a = acc[i];
          a = fmaf(xv.x, w0, a); a = fmaf(xv.y, w1, a);
          a = fmaf(xv.z, w2, a); a = fmaf(xv.w, w3, a);
          acc[i] = a;
        }
      }
    }
    for (int i = 0; i < nrows; ++i) sm.q[n0 + i][co] = acc[i] * sm.mw[n0 + i];
  }
  // k = y @ Wk
  {
    float acc[13];
#pragma unroll
    for (int i = 0; i < 13; ++i) acc[i] = 0.f;
#pragma unroll 2
    for (int c4 = 0; c4 < 48; ++c4) {
      const float w0 = Wk[(c4 * 4 + 0) * CCH + co];
      const float w1 = Wk[(c4 * 4 + 1) * CCH + co];
      const float w2 = Wk[(c4 * 4 + 2) * CCH + co];
      const float w3 = Wk[(c4 * 4 + 3) * CCH + co];
#pragma unroll
      for (int i = 0; i < 13; ++i) {
        if (i < nrows) {
          const float4 yv = *reinterpret_cast<const float4*>(y + gbase[i] + c4 * 4);
          float a = acc[i];
          a = fmaf(yv.x, w0, a); a = fmaf(yv.y, w1, a);
          a = fmaf(yv.z, w2, a); a = fmaf(yv.w, w3, a);
          acc[i] = a;
        }
      }
    }
    for (int i = 0; i < nrows; ++i) sm.k[n0 + i][co] = acc[i];
  }
  // v = y @ Wv
  {
    float acc[13];
#pragma unroll
    for (int i = 0; i < 13; ++i) acc[i] = 0.f;
#pragma unroll 2
    for (int c4 = 0; c4 < 48; ++c4) {
      const float w0 = Wv[(c4 * 4 + 0) * CCH + co];
      const float w1 = Wv[(c4 * 4 + 1) * CCH + co];
      const float w2 = Wv[(c4 * 4 + 2) * CCH + co];
      const float w3 = Wv[(c4 * 4 + 3) * CCH + co];
#pragma unroll
      for (int i = 0; i < 13; ++i) {
        if (i < nrows) {
          const float4 yv = *reinterpret_cast<const float4*>(y + gbase[i] + c4 * 4);
          float a = acc[i];
          a = fmaf(yv.x, w0, a); a = fmaf(yv.y, w1, a);
          a = fmaf(yv.z, w2, a); a = fmaf(yv.w, w3, a);
          acc[i] = a;
        }
      }
    }
    for (int i = 0; i < nrows; ++i) sm.v[n0 + i][co] = acc[i];
  }
  __syncthreads();

  // ---------- Per-head attention ----------
  const float scale = 0.17677669529663687f;  // 1/sqrt(32)
  const int att_base_w = w * (NH * NN * NN);
  for (int h = 0; h < NH; ++h) {
    const int hoff = h * DD;
    // logits[n][m] = scale * <q[n], k[m]> + log(mw[m]+1e-6)
    for (int i = tid; i < NN * NN; i += BLOCK) {
      const int n = i / NN, m = i % NN;
      const float4* qp = reinterpret_cast<const float4*>(&sm.q[n][hoff]);
      const float4* kp = reinterpret_cast<const float4*>(&sm.k[m][hoff]);
      float d = 0.f;
#pragma unroll
      for (int j = 0; j < 8; ++j) {
        const float4 a = qp[j], bb = kp[j];
        d = fmaf(a.x, bb.x, d); d = fmaf(a.y, bb.y, d);
        d = fmaf(a.z, bb.z, d); d = fmaf(a.w, bb.w, d);
      }
      sm.att[n][m] = d * scale + sm.logmw[m];
    }
    __syncthreads();
    // wave-parallel softmax over m, write att to global
    for (int n = wave; n < NN; n += 12) {
      const float vv = (lane < NN) ? sm.att[n][lane] : -INFINITY;
      const float mx = wave_reduce_max(vv);
      const float e = (lane < NN) ? expf(vv - mx) : 0.f;
      const float s = wave_reduce_sum(e);
      const float r = e / s;
      if (lane < NN) {
        sm.att[n][lane] = r;
        att_out[att_base_w + h * (NN * NN) + n * NN + lane] = r;
      }
    }
    __syncthreads();
    // PV: out[n][hoff+dd] = sum_m att[n][m] * v[m][hoff+dd]
    // written in-place into sm.q's columns of this head (q cols dead post-logits)
    for (int i = tid; i < NN * DD; i += BLOCK) {
      const int n = i >> 5;
      const int dd = i & 31;
      float a = 0.f;
#pragma unroll 7
      for (int m = 0; m < NN; ++m)
        a = fmaf(sm.att[n][m], sm.v[m][hoff + dd], a);
      sm.q[n][hoff + dd] = a;
    }
    __syncthreads();
  }

  // ---------- Output projection + scatter (roll(+SHIFT) == gather coords) ----------
  {
    float acc[13];
#pragma unroll
    for (int i = 0; i < 13; ++i) acc[i] = 0.f;
#pragma unroll 2
    for (int c4 = 0; c4 < 48; ++c4) {
      const float w0 = Wo[(c4 * 4 + 0) * CCH + co];
      const float w1 = Wo[(c4 * 4 + 1) * CCH + co];
      const float w2 = Wo[(c4 * 4 + 2) * CCH + co];
      const float w3 = Wo[(c4 * 4 + 3) * CCH + co];
#pragma unroll
      for (int i = 0; i < 13; ++i) {
        if (i < nrows) {
          const float4 ov = *reinterpret_cast<const float4*>(&sm.q[n0 + i][c4 * 4]);
          float a = acc[i];
          a = fmaf(ov.x, w0, a); a = fmaf(ov.y, w1, a);
          a = fmaf(ov.z, w2, a); a = fmaf(ov.w, w3, a);
          acc[i] = a;
        }
      }
    }
    for (int i = 0; i < nrows; ++i) out[gbase[i] + co] = acc[i];
  }
}

extern "C" void kernel_launch(void* const* d_in, const int* in_sizes, int n_in,
                              void* d_out, int out_size, void* d_ws, size_t ws_size,
                              hipStream_t stream) {
  const float* x  = (const float*)d_in[0];
  const float* y  = (const float*)d_in[1];
  const float* Wq = (const float*)d_in[2];
  const float* Wk = (const float*)d_in[3];
  const float* Wv = (const float*)d_in[4];
  const float* Wo = (const float*)d_in[5];
  float* out = (float*)d_out;
  float* att = (float*)d_out + OUT_ELEMS;

  const int smem_bytes = (int)sizeof(SMem);  // ~125.8 KB, needs opt-in >64KB
  (void)hipFuncSetAttribute((const void*)swin_cross_attn_kernel,
                            hipFuncAttributeMaxDynamicSharedMemorySize, smem_bytes);

  swin_cross_attn_kernel<<<dim3(NWIN), dim3(BLOCK), smem_bytes, stream>>>(
      x, y, Wq, Wk, Wv, Wo, out, att);
}